// Round 1
// baseline (299.675 us; speedup 1.0000x reference)
//
#include <hip/hip_runtime.h>

// CharBiLSTMEmbedder: N=32768 words, T=20, E=H=50, V=200, out [N,100] fp32.
//
// Round-7 (occupancy): Gl (84.8KB) removed from LDS -> G gate-preactivations
// read per-step straight from global (L2-resident, 13x dwordx2/lane, C-init
// of the MFMAs). LDS 127.5KB -> 45.6KB => 2 blocks/CU (4 waves/SIMD) with
// __launch_bounds__(512,4); pass1/pass2 split in 7/6-tile halves to keep
// VGPR <= 128. G and Whh images pre-scaled by +-log2e per gate so gate math
// is pure exp2: sig = rcp(1+exp2(acc)). Reverse-pair block remap (k, 511-k)
// balances long+short blocks on each CU now that all 512 blocks co-reside.

#define TT    20
#define HH    50
#define VV    200
#define TILES 13        // 13*16 = 208 rows >= 200
#define GSTR  212       // G row stride in shorts (53 units * 4 gates)
#define GSH   (VV * GSTR)        // 42400 shorts per dir
#define WSH   (TILES * 16 * 64)  // 13312 shorts per dir
#define NW    32768
#define NB_G  332       // ceil(2*GSH/256)
#define NB_W  104       // ceil(2*WSH/256)
#define NB_H  128       // 128*256 = 32768 words

#define LOG2E   1.4426950408889634f
#define N2LOG2E (-1.4426950408889634f)
#define P2LOG2E 2.8853900817779268f

typedef __attribute__((ext_vector_type(8))) short bf16x8;
typedef __attribute__((ext_vector_type(4))) short s16x4;
typedef __attribute__((ext_vector_type(4))) float f32x4;

__device__ __forceinline__ float frcp(float x) { return __builtin_amdgcn_rcpf(x); }
#if __has_builtin(__builtin_amdgcn_exp2f)
__device__ __forceinline__ float fexp2(float x) { return __builtin_amdgcn_exp2f(x); }
#else
__device__ __forceinline__ float fexp2(float x) { return exp2f(x); }
#endif

__device__ __forceinline__ short f2bf(float x) {  // RNE fp32 -> bf16
    unsigned b = __builtin_bit_cast(unsigned, x);
    unsigned r = (b + 0x7FFFu + ((b >> 16) & 1u)) >> 16;
    return (short)r;
}
__device__ __forceinline__ float bf2f(short s) {
    return __builtin_bit_cast(float, ((unsigned)(unsigned short)s) << 16);
}

// One kernel, three jobs by block range:
//  [0,NB_G): Gimg[d][v*GSTR+u*4+g] = bf16(sc_g*(emb'[v].W_ih[g*50+u] + b_ih + b_hh))
//  [NB_G,NB_G+NB_W): Wimg = MFMA A-operand image of sc_g*Whh (bf16, k-swizzled)
//  [NB_G+NB_W, +NB_H): cnt[block][21] = length histogram of 256 words
//  sc_g = -log2e for i,f,o rows; +2log2e for g rows (exp2-domain gates).
__global__ void k_prep(const float* __restrict__ emb,
                       const float* __restrict__ Wih_f, const float* __restrict__ bih_f,
                       const float* __restrict__ bhh_f,
                       const float* __restrict__ Wih_b, const float* __restrict__ bih_b,
                       const float* __restrict__ bhh_b,
                       const float* __restrict__ Whh_f, const float* __restrict__ Whh_b,
                       const int* __restrict__ lens,
                       short* __restrict__ Gimg, short* __restrict__ Wimg,
                       int* __restrict__ cnt) {
    int blk = blockIdx.x;
    int tid = threadIdx.x;
    if (blk < NB_G) {
        int idx = blk * 256 + tid;
        if (idx >= 2 * GSH) return;
        int d = idx / GSH;
        int rem = idx % GSH;
        int v = rem / GSTR;
        int u = (rem % GSTR) >> 2;
        int g = idx & 3;
        if (u >= HH) { Gimg[idx] = 0; return; }
        int r = g * HH + u;
        const float* Wih = d ? Wih_b : Wih_f;
        const float* bih = d ? bih_b : bih_f;
        const float* bhh = d ? bhh_b : bhh_f;
        float s = bih[r] + bhh[r];
        if (v != 0) {  // PAD row of emb is zero
            #pragma unroll 10
            for (int e = 0; e < HH; ++e) s = fmaf(emb[v * HH + e], Wih[r * HH + e], s);
        }
        float sc = (g == 2) ? P2LOG2E : N2LOG2E;
        Gimg[idx] = f2bf(s * sc);
    } else if (blk < NB_G + NB_W) {
        int idx = (blk - NB_G) * 256 + tid;
        if (idx >= 2 * WSH) return;
        int d = idx / WSH;
        int e = idx % WSH;
        int t = e >> 10, m = (e >> 6) & 15, k = e & 63;
        int u = 4 * t + (m >> 2), g = m & 3;
        const float* Whh = d ? Whh_b : Whh_f;
        float sc = (g == 2) ? P2LOG2E : N2LOG2E;
        float val = (k < HH && u < HH) ? Whh[(g * HH + u) * HH + k] * sc : 0.0f;
        int ksw = (k & 7) | (((k >> 3) ^ (m & 7)) << 3);
        Wimg[d * WSH + (e & ~63) + ksw] = f2bf(val);
    } else {
        int hb = blk - NB_G - NB_W;      // 0..127
        __shared__ int hcnt[21];
        if (tid < 21) hcnt[tid] = 0;
        __syncthreads();
        atomicAdd(&hcnt[lens[hb * 256 + tid]], 1);
        __syncthreads();
        if (tid < 21) cnt[hb * 21 + tid] = hcnt[tid];
    }
}

// offs[b][L] = start of (bucket L, block b) region; buckets ordered L=20..0.
// 21 buckets x 8 chunks of 16 blocks: serial loops are 16-21 long, not 128.
__global__ void k_scan(const int* __restrict__ cnt, int* __restrict__ offs) {
    __shared__ int part[8][21];
    __shared__ int tot[21], start[21];
    int t = threadIdx.x;              // 0..255, 168 active in chunk phases
    int L = t % 21, c = t / 21;
    if (t < 168) {
        int s = 0;
        for (int b = c * 16; b < c * 16 + 16; ++b) s += cnt[b * 21 + L];
        part[c][L] = s;
    }
    __syncthreads();
    if (t < 21) {
        int a = 0;
        #pragma unroll
        for (int c2 = 0; c2 < 8; ++c2) a += part[c2][t];
        tot[t] = a;
    }
    __syncthreads();
    if (t == 0) {
        int acc = 0;
        for (int Lq = 20; Lq >= 0; --Lq) { start[Lq] = acc; acc += tot[Lq]; }
    }
    __syncthreads();
    if (t < 168) {
        int base = start[L];
        for (int c2 = 0; c2 < c; ++c2) base += part[c2][L];
        for (int b = c * 16; b < c * 16 + 16; ++b) {
            offs[b * 21 + L] = base;
            base += cnt[b * 21 + L];
        }
    }
}

__global__ void k_scat(const int* __restrict__ lens, const int* __restrict__ offs,
                       int* __restrict__ perm) {
    __shared__ int cur[21];
    int b = blockIdx.x, t = threadIdx.x;
    if (t < 21) cur[t] = offs[b * 21 + t];
    __syncthreads();
    int i = b * 256 + t;
    int pos = atomicAdd(&cur[lens[i]], 1);
    perm[pos] = i;
}

__launch_bounds__(512, 4)
__global__ void k_lstm(const int* __restrict__ chars, const int* __restrict__ lens,
                       const int* __restrict__ perm,
                       const short* __restrict__ Gimg, const short* __restrict__ Wimg,
                       float* __restrict__ out) {
    __shared__ __align__(16) short Wa[WSH];        // 26624 B
    __shared__ __align__(16) short hs[8][1024];    // 16384 B per-wave h (bf16)
    __shared__ unsigned char cs[8][320];           // 2560 B per-wave chars (u8)
    // total LDS 45568 B -> 2 blocks/CU (VGPR-capped at 128 by launch_bounds)

    int gb   = blockIdx.x;             // 0..511
    // reverse-pair remap: dispatch places gb=k and gb=k+256 on the same CU
    // (XCD round-robin); rank pairs longest with shortest so per-CU work sums
    // are ~constant now that all 512 blocks are co-resident.
    int rank = (gb < 256) ? gb : (767 - gb);
    int d    = rank & 1;
    int grp  = rank >> 1;              // 0..255
    int tid  = threadIdx.x;            // 0..511
    int lane = tid & 63;
    int wv   = __builtin_amdgcn_readfirstlane(tid >> 6);   // 0..7
    int quad = lane >> 4;
    int n    = lane & 15;
    int x7   = n & 7;

    // ---- stage: coalesced block copies (Whh image only; G stays in L2) ----
    {
        const int4* src = (const int4*)(Wimg + d * WSH);
        int4* dst = (int4*)Wa;
        for (int i = tid; i < WSH / 8; i += 512) dst[i] = src[i];
    }
    {
        int4 z = {0, 0, 0, 0};
        int4* hz = (int4*)&hs[0][0];
        for (int i = tid; i < 8 * 1024 / 8; i += 512) hz[i] = z;
    }
    int slotbase = (grp * 8 + wv) * 16;        // wave's first sorted slot
    for (int i = lane; i < 16 * TT; i += 64) {
        int w = perm[slotbase + i / TT];
        cs[wv][i] = (unsigned char)chars[w * TT + i % TT];
    }
    __syncthreads();

    int word = perm[slotbase + n];
    int L = lens[word];
    int mL = L;
    #pragma unroll
    for (int off = 8; off; off >>= 1) {
        int t2 = __shfl_xor(mL, off);
        mL = mL > t2 ? mL : t2;
    }
    mL = __builtin_amdgcn_readfirstlane(mL);

    const bf16x8* ap = (const bf16x8*)Wa;
    const bf16x8* bp = (const bf16x8*)hs[wv];
    short* hw = hs[wv];
    const unsigned char* cw = cs[wv] + n * TT;
    const short* Gg = Gimg + d * GSH;          // global, L2-resident

    int pa0 = quad ^ x7;           // swizzled k-group, k 0..31
    int pa1 = (quad + 4) ^ x7;     // k 32..63

    float cst[TILES], hf[TILES];
    #pragma unroll
    for (int t = 0; t < TILES; ++t) { cst[t] = 0.0f; hf[t] = 0.0f; }

    int p0 = d ? (L > 0 ? L - 1 : 0) : 0;      // prefetch first char
    int vcur = cw[p0];

    #pragma unroll 1
    for (int s = 0; s < mL; ++s) {
        bool valid = s < L;

        // issue this step's 13 G loads (dwordx2 from L2) first: consumed as
        // MFMA C-init, so B ds_reads + char prefetch cover their latency.
        const short* gvp = Gg + vcur * GSTR + quad * 4;
        s16x4 gv[TILES];
        #pragma unroll
        for (int t = 0; t < TILES; ++t) gv[t] = *(const s16x4*)(gvp + t * 16);

        bf16x8 B0 = bp[n * 8 + pa0];     // h of step s-1, B-operand layout
        bf16x8 B1 = bp[n * 8 + pa1];

        int sn = s + 1;                  // prefetch next step's char id
        int pn = (sn < L) ? (d ? (L - 1 - sn) : sn) : 0;
        vcur = cw[pn];

        // two 7/6-tile halves keep acc+gv peak VGPR under the 128 cap
        #pragma unroll
        for (int half = 0; half < 2; ++half) {
            const int t0 = half ? 7 : 0;
            const int t1 = half ? TILES : 7;
            f32x4 acc[7];
            #pragma unroll
            for (int t = t0; t < t1; ++t) {
                f32x4 a;
                a[0] = bf2f(gv[t][0]); a[1] = bf2f(gv[t][1]);
                a[2] = bf2f(gv[t][2]); a[3] = bf2f(gv[t][3]);
                bf16x8 A0 = ap[(t * 16 + n) * 8 + pa0];
                bf16x8 A1 = ap[(t * 16 + n) * 8 + pa1];
                a = __builtin_amdgcn_mfma_f32_16x16x32_bf16(A0, B0, a, 0, 0, 0);
                a = __builtin_amdgcn_mfma_f32_16x16x32_bf16(A1, B1, a, 0, 0, 0);
                acc[t - t0] = a;
            }
            // gate math in exp2 domain (scales baked into Gimg/Wimg):
            //   sig(x) = rcp(1+2^(-x*log2e)), tanh(x) = 1-2*rcp(1+2^(2x*log2e))
            #pragma unroll
            for (int t = t0; t < t1; ++t) {
                f32x4 a = acc[t - t0];
                int u = 4 * t + quad;
                float ig = frcp(1.0f + fexp2(a[0]));
                float fg = frcp(1.0f + fexp2(a[1]));
                float tg = 1.0f - 2.0f * frcp(1.0f + fexp2(a[2]));
                float og = frcp(1.0f + fexp2(a[3]));
                float cold = cst[t];
                float cn = fg * cold + ig * tg;
                float hn = og * (1.0f - 2.0f * frcp(1.0f + fexp2(cn * P2LOG2E)));
                bool upd = valid && (u < HH);
                cst[t] = upd ? cn : cold;
                hf[t]  = upd ? hn : hf[t];
                if (upd) {
                    int idx = n * 64 + (((u >> 3) ^ x7) << 3) + (u & 7);
                    hw[idx] = f2bf(hn);      // skipped when invalid -> h frozen
                }
            }
        }
    }

    float* orow = out + (size_t)word * (2 * HH) + d * HH;
    #pragma unroll
    for (int t = 0; t < TILES; ++t) {
        int u = 4 * t + quad;
        if (u < HH) orow[u] = hf[t];     // fp32 h
    }
}

extern "C" void kernel_launch(void* const* d_in, const int* in_sizes, int n_in,
                              void* d_out, int out_size, void* d_ws, size_t ws_size,
                              hipStream_t stream) {
    const int*   chars = (const int*)d_in[0];
    const int*   lens  = (const int*)d_in[1];
    const float* emb   = (const float*)d_in[2];
    const float* Wih_f = (const float*)d_in[3];
    const float* Whh_f = (const float*)d_in[4];
    const float* bih_f = (const float*)d_in[5];
    const float* bhh_f = (const float*)d_in[6];
    const float* Wih_b = (const float*)d_in[7];
    const float* Whh_b = (const float*)d_in[8];
    const float* bih_b = (const float*)d_in[9];
    const float* bhh_b = (const float*)d_in[10];
    float* out = (float*)d_out;

    short* Gimg = (short*)d_ws;                 // 169600 B
    short* Wimg = Gimg + 2 * GSH;               //  53248 B
    int*   cnt  = (int*)(Wimg + 2 * WSH);       //  10752 B
    int*   offs = cnt + NB_H * 21;              //  10752 B
    int*   perm = offs + NB_H * 21;             // 131072 B   (total ~375 KB)

    k_prep<<<NB_G + NB_W + NB_H, 256, 0, stream>>>(emb, Wih_f, bih_f, bhh_f,
                                                   Wih_b, bih_b, bhh_b,
                                                   Whh_f, Whh_b, lens,
                                                   Gimg, Wimg, cnt);
    k_scan<<<1, 256, 0, stream>>>(cnt, offs);
    k_scat<<<NB_H, 256, 0, stream>>>(lens, offs, perm);
    k_lstm<<<512, 512, 0, stream>>>(chars, lens, perm, Gimg, Wimg, out);
}

// Round 2
// 146.334 us; speedup vs baseline: 2.0479x; 2.0479x over previous
//
#include <hip/hip_runtime.h>

// CharBiLSTMEmbedder: N=32768 words, T=20, E=H=50, V=200, out [N,100] fp32.
//
// Round-8: block = 16 words x 8 waves; the 13 u-tiles are SPLIT ACROSS WAVES
// (waves 0-4: 2 tiles, 5-7: 1 tile) so per-wave register state is tiny and
// the Whh A-fragments live in REGISTERS (loaded once from L2). LDS is just a
// double-buffered h (4KB) + chars (320B) -> 4 blocks/CU, 32 waves/CU.
// One __syncthreads per step (h dbuf). G preactivations stay in global (L2),
// exp2-domain gates (scales baked into Gimg/Wimg). k_scan folded into k_scat.
// Round-1 lesson: no forced launch_bounds squeeze (spills cost 3x); cap 85.

#define TT    20
#define HH    50
#define VV    200
#define TILES 13        // 13*16 = 208 rows >= 200
#define GSTR  212       // G row stride in shorts (53 units * 4 gates)
#define GSH   (VV * GSTR)        // 42400 shorts per dir
#define WSH   (TILES * 16 * 64)  // 13312 shorts per dir
#define NW    32768
#define NB_G  332       // ceil(2*GSH/256)
#define NB_W  104       // ceil(2*WSH/256)
#define NB_H  128       // 128*256 = 32768 words
#define NBLK  4096      // 2 dirs * 32768/16 words

#define N2LOG2E (-1.4426950408889634f)
#define P2LOG2E 2.8853900817779268f

typedef __attribute__((ext_vector_type(8))) short bf16x8;
typedef __attribute__((ext_vector_type(4))) short s16x4;
typedef __attribute__((ext_vector_type(4))) float f32x4;

__device__ __forceinline__ float frcp(float x) { return __builtin_amdgcn_rcpf(x); }
#if __has_builtin(__builtin_amdgcn_exp2f)
__device__ __forceinline__ float fexp2(float x) { return __builtin_amdgcn_exp2f(x); }
#else
__device__ __forceinline__ float fexp2(float x) { return exp2f(x); }
#endif

__device__ __forceinline__ short f2bf(float x) {  // RNE fp32 -> bf16
    unsigned b = __builtin_bit_cast(unsigned, x);
    unsigned r = (b + 0x7FFFu + ((b >> 16) & 1u)) >> 16;
    return (short)r;
}
__device__ __forceinline__ float bf2f(short s) {
    return __builtin_bit_cast(float, ((unsigned)(unsigned short)s) << 16);
}

// One kernel, three jobs by block range:
//  [0,NB_G): Gimg[d][v*GSTR+u*4+g] = bf16(sc_g*(emb'[v].W_ih[g*50+u] + b_ih + b_hh))
//  [NB_G,NB_G+NB_W): Wimg = MFMA A-operand image of sc_g*Whh (bf16, k-swizzled)
//  [NB_G+NB_W, +NB_H): cnt[block][21] = length histogram of 256 words
//  sc_g = -log2e for i,f,o rows; +2log2e for g rows (exp2-domain gates).
__global__ void k_prep(const float* __restrict__ emb,
                       const float* __restrict__ Wih_f, const float* __restrict__ bih_f,
                       const float* __restrict__ bhh_f,
                       const float* __restrict__ Wih_b, const float* __restrict__ bih_b,
                       const float* __restrict__ bhh_b,
                       const float* __restrict__ Whh_f, const float* __restrict__ Whh_b,
                       const int* __restrict__ lens,
                       short* __restrict__ Gimg, short* __restrict__ Wimg,
                       int* __restrict__ cnt) {
    int blk = blockIdx.x;
    int tid = threadIdx.x;
    if (blk < NB_G) {
        int idx = blk * 256 + tid;
        if (idx >= 2 * GSH) return;
        int d = idx / GSH;
        int rem = idx % GSH;
        int v = rem / GSTR;
        int u = (rem % GSTR) >> 2;
        int g = idx & 3;
        if (u >= HH) { Gimg[idx] = 0; return; }
        int r = g * HH + u;
        const float* Wih = d ? Wih_b : Wih_f;
        const float* bih = d ? bih_b : bih_f;
        const float* bhh = d ? bhh_b : bhh_f;
        float s = bih[r] + bhh[r];
        if (v != 0) {  // PAD row of emb is zero
            #pragma unroll 10
            for (int e = 0; e < HH; ++e) s = fmaf(emb[v * HH + e], Wih[r * HH + e], s);
        }
        float sc = (g == 2) ? P2LOG2E : N2LOG2E;
        Gimg[idx] = f2bf(s * sc);
    } else if (blk < NB_G + NB_W) {
        int idx = (blk - NB_G) * 256 + tid;
        if (idx >= 2 * WSH) return;
        int d = idx / WSH;
        int e = idx % WSH;
        int t = e >> 10, m = (e >> 6) & 15, k = e & 63;
        int u = 4 * t + (m >> 2), g = m & 3;
        const float* Whh = d ? Whh_b : Whh_f;
        float sc = (g == 2) ? P2LOG2E : N2LOG2E;
        float val = (k < HH && u < HH) ? Whh[(g * HH + u) * HH + k] * sc : 0.0f;
        int ksw = (k & 7) | (((k >> 3) ^ (m & 7)) << 3);
        Wimg[d * WSH + (e & ~63) + ksw] = f2bf(val);
    } else {
        int hb = blk - NB_G - NB_W;      // 0..127
        __shared__ int hcnt[21];
        if (tid < 21) hcnt[tid] = 0;
        __syncthreads();
        atomicAdd(&hcnt[lens[hb * 256 + tid]], 1);
        __syncthreads();
        if (tid < 21) cnt[hb * 21 + tid] = hcnt[tid];
    }
}

// Merged scan+scatter: every block stages the 128x21 histogram into LDS,
// computes its own bucket offsets (buckets ordered L=20..0, LPT), scatters
// its 256 words. Removes the separate 1-block k_scan launch.
__global__ void k_scat(const int* __restrict__ lens, const int* __restrict__ cnt,
                       int* __restrict__ perm) {
    __shared__ int lcnt[NB_H * 21];     // 10752 B
    __shared__ int part[8][21];
    __shared__ int tot[21];
    __shared__ int cur[21];
    int b = blockIdx.x, t = threadIdx.x;
    for (int i = t; i < NB_H * 21; i += 256) lcnt[i] = cnt[i];
    __syncthreads();
    if (t < 168) {
        int L = t % 21, c = t / 21;
        int s = 0;
        for (int bb = c * 16; bb < c * 16 + 16; ++bb) s += lcnt[bb * 21 + L];
        part[c][L] = s;
    }
    __syncthreads();
    if (t < 21) {
        int a = 0;
        #pragma unroll
        for (int c = 0; c < 8; ++c) a += part[c][t];
        tot[t] = a;
    }
    __syncthreads();
    if (t < 21) {
        int a = 0;
        for (int L2 = 20; L2 > t; --L2) a += tot[L2];   // start of bucket t
        for (int bb = 0; bb < b; ++bb) a += lcnt[bb * 21 + t];
        cur[t] = a;
    }
    __syncthreads();
    int i = b * 256 + t;
    int pos = atomicAdd(&cur[lens[i]], 1);
    perm[pos] = i;
}

// Block = one dir x 16 sorted-adjacent words; 8 waves split the 13 u-tiles.
// LDS: h double-buffer (2x1024 shorts) + chars. A-frags & state in registers.
__launch_bounds__(512, 6)
__global__ void k_lstm(const int* __restrict__ chars, const int* __restrict__ lens,
                       const int* __restrict__ perm,
                       const short* __restrict__ Gimg, const short* __restrict__ Wimg,
                       float* __restrict__ out) {
    __shared__ __align__(16) short hs[2][1024];    // 4096 B
    __shared__ unsigned char cs[16 * TT];          // 320 B

    int gb   = blockIdx.x;             // 0..4095, LPT (longest groups first)
    int d    = gb & 1;
    int grp  = gb >> 1;                // 0..2047
    int tid  = threadIdx.x;            // 0..511
    int lane = tid & 63;
    int wv   = __builtin_amdgcn_readfirstlane(tid >> 6);   // 0..7
    int quad = lane >> 4;
    int n    = lane & 15;
    int x7   = n & 7;
    int slotbase = grp * 16;

    {   // zero both h buffers (2048 shorts = 256 int4)
        int4 z = {0, 0, 0, 0};
        int4* hz = (int4*)&hs[0][0];
        if (tid < 256) hz[tid] = z;
    }
    for (int i = tid; i < 16 * TT; i += 512) {     // block's chars, shared
        int w = perm[slotbase + i / TT];
        cs[i] = (unsigned char)chars[w * TT + i % TT];
    }

    int word = perm[slotbase + n];
    int L = lens[word];
    int mL = L;                         // block-max length (same 16 words
    #pragma unroll                      //  for every wave -> block-uniform)
    for (int off = 8; off; off >>= 1) {
        int t2 = __shfl_xor(mL, off);
        mL = mL > t2 ? mL : t2;
    }
    mL = __builtin_amdgcn_readfirstlane(mL);

    int pa0 = quad ^ x7;               // swizzled k-group, k 0..31
    int pa1 = (quad + 4) ^ x7;         // k 32..63

    // this wave's tiles: tA = wv, tB = wv+8 (waves 5..7 have only tA)
    int tA = wv, tB = wv + 8;
    int nt = (wv < 5) ? 2 : 1;
    int uA = 4 * tA + quad;
    int uB = 4 * tB + quad;
    int hidxA = n * 64 + (((uA >> 3) ^ x7) << 3) + (uA & 7);
    int hidxB = n * 64 + (((uB >> 3) ^ x7) << 3) + (uB & 7);

    // A fragments (Whh image) live in registers; one-time read from L2
    const short* Wd = Wimg + d * WSH;
    bf16x8 A0a = *(const bf16x8*)(Wd + (tA * 16 + n) * 64 + pa0 * 8);
    bf16x8 A1a = *(const bf16x8*)(Wd + (tA * 16 + n) * 64 + pa1 * 8);
    bf16x8 A0b, A1b;
    if (nt == 2) {
        A0b = *(const bf16x8*)(Wd + (tB * 16 + n) * 64 + pa0 * 8);
        A1b = *(const bf16x8*)(Wd + (tB * 16 + n) * 64 + pa1 * 8);
    }

    const short* Gg = Gimg + d * GSH;  // gate preactivations, L2-resident
    const unsigned char* cw = cs + n * TT;

    float cstA = 0.0f, hfA = 0.0f, cstB = 0.0f, hfB = 0.0f;

    __syncthreads();

    int vcur = cw[(d && L > 0) ? (L - 1) : 0];
    int cur = 0;

    #pragma unroll 1
    for (int s = 0; s < mL; ++s) {
        bool valid = s < L;

        // this step's G loads (8B each, L2); latency covered by B reads+MFMA
        const short* gvp = Gg + vcur * GSTR + quad * 4;
        s16x4 gvA = *(const s16x4*)(gvp + tA * 16);
        s16x4 gvB;
        if (nt == 2) gvB = *(const s16x4*)(gvp + tB * 16);

        const short* hb = hs[cur];
        bf16x8 B0 = *(const bf16x8*)(hb + n * 64 + pa0 * 8);
        bf16x8 B1 = *(const bf16x8*)(hb + n * 64 + pa1 * 8);

        int sn = s + 1;                 // prefetch next char id
        int pn = (sn < L) ? (d ? (L - 1 - sn) : sn) : 0;
        vcur = cw[pn];

        f32x4 aA;
        aA[0] = bf2f(gvA[0]); aA[1] = bf2f(gvA[1]);
        aA[2] = bf2f(gvA[2]); aA[3] = bf2f(gvA[3]);
        aA = __builtin_amdgcn_mfma_f32_16x16x32_bf16(A0a, B0, aA, 0, 0, 0);
        aA = __builtin_amdgcn_mfma_f32_16x16x32_bf16(A1a, B1, aA, 0, 0, 0);
        f32x4 aB;
        if (nt == 2) {
            aB[0] = bf2f(gvB[0]); aB[1] = bf2f(gvB[1]);
            aB[2] = bf2f(gvB[2]); aB[3] = bf2f(gvB[3]);
            aB = __builtin_amdgcn_mfma_f32_16x16x32_bf16(A0b, B0, aB, 0, 0, 0);
            aB = __builtin_amdgcn_mfma_f32_16x16x32_bf16(A1b, B1, aB, 0, 0, 0);
        }

        // gates in exp2 domain: sig(x)=rcp(1+2^(-x*log2e)), tanh via 2^(2x*log2e)
        {
            float ig = frcp(1.0f + fexp2(aA[0]));
            float fg = frcp(1.0f + fexp2(aA[1]));
            float tg = 1.0f - 2.0f * frcp(1.0f + fexp2(aA[2]));
            float og = frcp(1.0f + fexp2(aA[3]));
            float cn = fg * cstA + ig * tg;
            float hn = og * (1.0f - 2.0f * frcp(1.0f + fexp2(cn * P2LOG2E)));
            bool upd = valid && (uA < HH);
            cstA = upd ? cn : cstA;
            hfA  = upd ? hn : hfA;
        }
        if (nt == 2) {
            float ig = frcp(1.0f + fexp2(aB[0]));
            float fg = frcp(1.0f + fexp2(aB[1]));
            float tg = 1.0f - 2.0f * frcp(1.0f + fexp2(aB[2]));
            float og = frcp(1.0f + fexp2(aB[3]));
            float cn = fg * cstB + ig * tg;
            float hn = og * (1.0f - 2.0f * frcp(1.0f + fexp2(cn * P2LOG2E)));
            bool upd = valid && (uB < HH);
            cstB = upd ? cn : cstB;
            hfB  = upd ? hn : hfB;
        }

        // publish h (frozen value when invalid) into the other buffer
        short* hnb = hs[cur ^ 1];
        if (uA < HH) hnb[hidxA] = f2bf(hfA);
        if (nt == 2 && uB < HH) hnb[hidxB] = f2bf(hfB);
        __syncthreads();
        cur ^= 1;
    }

    float* orow = out + (size_t)word * (2 * HH) + d * HH;
    if (uA < HH) orow[uA] = hfA;
    if (nt == 2 && uB < HH) orow[uB] = hfB;
}

extern "C" void kernel_launch(void* const* d_in, const int* in_sizes, int n_in,
                              void* d_out, int out_size, void* d_ws, size_t ws_size,
                              hipStream_t stream) {
    const int*   chars = (const int*)d_in[0];
    const int*   lens  = (const int*)d_in[1];
    const float* emb   = (const float*)d_in[2];
    const float* Wih_f = (const float*)d_in[3];
    const float* Whh_f = (const float*)d_in[4];
    const float* bih_f = (const float*)d_in[5];
    const float* bhh_f = (const float*)d_in[6];
    const float* Wih_b = (const float*)d_in[7];
    const float* Whh_b = (const float*)d_in[8];
    const float* bih_b = (const float*)d_in[9];
    const float* bhh_b = (const float*)d_in[10];
    float* out = (float*)d_out;

    short* Gimg = (short*)d_ws;                 // 169600 B
    short* Wimg = Gimg + 2 * GSH;               //  53248 B
    int*   cnt  = (int*)(Wimg + 2 * WSH);       //  10752 B
    int*   perm = cnt + NB_H * 21;              // 131072 B   (total ~365 KB)

    k_prep<<<NB_G + NB_W + NB_H, 256, 0, stream>>>(emb, Wih_f, bih_f, bhh_f,
                                                   Wih_b, bih_b, bhh_b,
                                                   Whh_f, Whh_b, lens,
                                                   Gimg, Wimg, cnt);
    k_scat<<<NB_H, 256, 0, stream>>>(lens, cnt, perm);
    k_lstm<<<NBLK, 512, 0, stream>>>(chars, lens, perm, Gimg, Wimg, out);
}